// Round 1
// baseline (431.883 us; speedup 1.0000x reference)
//
#include <hip/hip_runtime.h>
#include <hip/hip_bf16.h>

#define BS 4
#define N 4096
#define NW 64            // N/64 bit-words
#define MASK_ROWS 4112   // N + 16 pad rows so scan prefetch never branches
#define SCORE_THR 0.1f
#define IOU_THR 0.3f
#define MAX_COORD 4096.0f

// ---------------------------------------------------------------------------
// K1: per-image bitonic sort of packed (desc-score, asc-idx) keys in LDS.
// Emits sorted class-offset boxes (float4), sorted original idx, valid bits.
// ---------------------------------------------------------------------------
__global__ __launch_bounds__(1024) void k_sort(const float* __restrict__ preds,
                                               float4* __restrict__ sbox,
                                               int* __restrict__ sidx,
                                               unsigned long long* __restrict__ svalidW) {
    __shared__ unsigned long long keys[N];
    const int b = blockIdx.x;
    const float* P = preds + (size_t)b * N * 6;

    for (int p = threadIdx.x; p < N; p += 1024) {
        float s = P[p * 6 + 4];
        bool valid = (s >= SCORE_THR);
        float kf = valid ? s : -INFINITY;
        unsigned u = __float_as_uint(kf);
        // monotone ascending map for floats, then invert for descending
        u = (u & 0x80000000u) ? ~u : (u | 0x80000000u);
        unsigned desc = ~u;
        keys[p] = ((unsigned long long)desc << 32) | (unsigned)p;
    }
    __syncthreads();

    // ascending bitonic sort => (score desc, idx asc) — matches stable argsort
    for (int k = 2; k <= N; k <<= 1) {
        for (int j = k >> 1; j > 0; j >>= 1) {
            for (int t = threadIdx.x; t < N; t += 1024) {
                int ixj = t ^ j;
                if (ixj > t) {
                    bool up = ((t & k) == 0);
                    unsigned long long a = keys[t], c = keys[ixj];
                    if ((a > c) == up) { keys[t] = c; keys[ixj] = a; }
                }
            }
            __syncthreads();
        }
    }

    for (int p = threadIdx.x; p < N; p += 1024) {
        int idx = (int)(keys[p] & 0xFFFFFFFFull);
        const float* R = P + (size_t)idx * 6;
        float x1 = R[0], y1 = R[1], x2 = R[2], y2 = R[3], sc = R[4], cl = R[5];
        float off = cl * MAX_COORD;
        sbox[b * N + p] = make_float4(x1 + off, y1 + off, x2 + off, y2 + off);
        sidx[b * N + p] = idx;
        bool valid = (sc >= SCORE_THR);
        unsigned long long m = __ballot(valid);
        if ((threadIdx.x & 63) == 0) svalidW[b * NW + (p >> 6)] = m;
    }
}

// ---------------------------------------------------------------------------
// K2: suppression bit-matrix. mask[b][row][w] bit jj = (iou(row, w*64+jj) > thr
// && col > row). Lower-triangle words written as 0 so the scan can OR blindly.
// grid (64 rowblocks, BS), block 256 = 64 rows x 4 word-groups.
// ---------------------------------------------------------------------------
__global__ __launch_bounds__(256) void k_mask(const float4* __restrict__ sbox,
                                              unsigned long long* __restrict__ mask) {
    const int b = blockIdx.y;
    const int rb = blockIdx.x;
    const int r = threadIdx.x & 63;
    const int g = threadIdx.x >> 6;
    const int row = rb * 64 + r;
    const float4* S = sbox + b * N;
    const float4 rbx = S[row];
    const float rarea = (rbx.z - rbx.x) * (rbx.w - rbx.y);
    unsigned long long* M = mask + (size_t)b * MASK_ROWS * NW;

    for (int wc = g; wc < NW; wc += 4) {
        unsigned long long word = 0;
        if (wc >= rb) {
            const int jbase = wc * 64;
#pragma unroll 8
            for (int jj = 0; jj < 64; ++jj) {
                int j = jbase + jj;
                float4 cbx = S[j];
                float carea = (cbx.z - cbx.x) * (cbx.w - cbx.y);
                float ix1 = fmaxf(rbx.x, cbx.x), iy1 = fmaxf(rbx.y, cbx.y);
                float ix2 = fminf(rbx.z, cbx.z), iy2 = fminf(rbx.w, cbx.w);
                float iw = fmaxf(ix2 - ix1, 0.0f), ih = fmaxf(iy2 - iy1, 0.0f);
                float inter = iw * ih;
                float iou = inter / (rarea + carea - inter + 1e-9f);
                if (iou > IOU_THR && j > row) word |= (1ull << jj);
            }
        }
        M[(size_t)row * NW + wc] = word;
    }
}

// ---------------------------------------------------------------------------
// K3: serial greedy scan, one wave per image. Lane l holds removed word l.
// removed starts as ~valid, so keep_i == !removed_bit_i. 16-deep prefetch ring.
// ---------------------------------------------------------------------------
__global__ __launch_bounds__(64) void k_scan(const unsigned long long* __restrict__ mask,
                                             const unsigned long long* __restrict__ svalidW,
                                             unsigned long long* __restrict__ keptW) {
    const int b = blockIdx.x;
    const int lane = threadIdx.x;
    const unsigned long long* M = mask + (size_t)b * MASK_ROWS * NW;

    unsigned long long removed = ~svalidW[b * NW + lane];
    unsigned long long keptword = 0;
    unsigned long long kw = 0;

    unsigned long long pf[16];
#pragma unroll
    for (int k = 0; k < 16; ++k) pf[k] = M[(size_t)k * NW + lane];

    for (int ib = 0; ib < N / 16; ++ib) {
#pragma unroll
        for (int u = 0; u < 16; ++u) {
            const int i = ib * 16 + u;
            unsigned long long row = pf[u];
            pf[u] = M[(size_t)(i + 16) * NW + lane];   // rows < MASK_ROWS (padded)

            const int wi = i >> 6;
            const int bit = i & 63;
            unsigned rl = (unsigned)removed;
            unsigned rh = (unsigned)(removed >> 32);
            unsigned wsel = (bit & 32) ? rh : rl;
            unsigned sv = (unsigned)__builtin_amdgcn_readlane((int)wsel, wi);
            bool keep = (((sv >> (bit & 31)) & 1u) == 0u);
            if (keep) {
                removed |= row;
                kw |= (1ull << bit);
            }
            if (bit == 63) {
                if (lane == wi) keptword = kw;
                kw = 0;
            }
        }
    }
    keptW[b * NW + lane] = keptword;
}

// ---------------------------------------------------------------------------
// K4: scatter output. Each sorted position maps to a unique original row.
// ---------------------------------------------------------------------------
__global__ __launch_bounds__(256) void k_out(const float* __restrict__ preds,
                                             const int* __restrict__ sidx,
                                             const unsigned long long* __restrict__ keptW,
                                             float* __restrict__ out) {
    const int b = blockIdx.y;
    const int p = blockIdx.x * 256 + threadIdx.x;
    const int idx = sidx[b * N + p];
    const bool keep = (keptW[b * NW + (p >> 6)] >> (p & 63)) & 1ull;
    const float* R = preds + ((size_t)b * N + idx) * 6;
    float* O = out + ((size_t)b * N + idx) * 6;
#pragma unroll
    for (int q = 0; q < 6; ++q) O[q] = keep ? R[q] : 0.0f;
}

extern "C" void kernel_launch(void* const* d_in, const int* in_sizes, int n_in,
                              void* d_out, int out_size, void* d_ws, size_t ws_size,
                              hipStream_t stream) {
    const float* preds = (const float*)d_in[0];
    float* out = (float*)d_out;

    // ws layout (8B/16B aligned throughout):
    // [mask: BS*MASK_ROWS*NW u64][sbox: BS*N float4][sidx: BS*N int]
    // [svalidW: BS*NW u64][keptW: BS*NW u64]
    unsigned long long* mask = (unsigned long long*)d_ws;
    char* p = (char*)d_ws + (size_t)BS * MASK_ROWS * NW * sizeof(unsigned long long);
    float4* sbox = (float4*)p;                 p += (size_t)BS * N * sizeof(float4);
    int* sidx = (int*)p;                       p += (size_t)BS * N * sizeof(int);
    unsigned long long* svalidW = (unsigned long long*)p;  p += (size_t)BS * NW * 8;
    unsigned long long* keptW = (unsigned long long*)p;

    k_sort<<<BS, 1024, 0, stream>>>(preds, sbox, sidx, svalidW);
    k_mask<<<dim3(64, BS), 256, 0, stream>>>(sbox, mask);
    k_scan<<<BS, 64, 0, stream>>>(mask, svalidW, keptW);
    k_out<<<dim3(N / 256, BS), 256, 0, stream>>>(preds, sidx, keptW, out);
}